// Round 3
// baseline (958.172 us; speedup 1.0000x reference)
//
#include <hip/hip_runtime.h>
#include <hip/hip_bf16.h>

#define VOCAB 50257
#define HID   1024
#define MAXLEN 64
#define G_PRE 1024
#define G_LOG 1024

__device__ __forceinline__ float dot4(float4 a, float4 b){
  return a.x*b.x + a.y*b.y + a.z*b.z + a.w*b.w;
}
__device__ __forceinline__ float dot4f(float4 a, const float* v){
  return a.x*v[0] + a.y*v[1] + a.z*v[2] + a.w*v[3];
}
__device__ __forceinline__ float wave_sum(float acc){
  #pragma unroll
  for (int k=32;k>=1;k>>=1) acc += __shfl_xor(acc,k);
  return acc;   // butterfly: all 64 lanes hold the sum
}

// Device-scope grid barrier. One counter per barrier site, zeroed by k_init.
// All blocks must be co-resident (guaranteed: grid = 4 blocks/CU, VGPR<=128).
__device__ __forceinline__ void gbar(unsigned* cnt, unsigned target){
  __syncthreads();
  if (threadIdx.x==0){
    __hip_atomic_fetch_add(cnt, 1u, __ATOMIC_RELEASE, __HIP_MEMORY_SCOPE_AGENT);
    while (__hip_atomic_load(cnt, __ATOMIC_ACQUIRE, __HIP_MEMORY_SCOPE_AGENT) < target)
      __builtin_amdgcn_s_sleep(8);
  }
  __syncthreads();
}

__global__ __launch_bounds__(64) void k_init(unsigned* bar){
  if (threadIdx.x < 16) bar[threadIdx.x] = 0u;
}

// ws float offsets: [0..15]=barrier counters (as uint), 64=scores(64),
// 128=attn(1024), 1280=x(1024), 2304=gi(3072), 5376=gh(3072), 8448=h(1024),
// 9600=stats(2048)
__global__ __launch_bounds__(256,4) void k_pre(
    const int* tok_p, const float* hidden, const float* enc, const float* emb,
    const float* attn_W, const float* attn_b,
    const float* comb_W, const float* comb_b,
    const float* Wih, const float* Whh, const float* bih, const float* bhh,
    float* out_h, float* out_attn, unsigned* bar, float* ws)
{
  float* ws_scores = ws + 64;
  float* ws_attn   = ws + 128;
  float* ws_x      = ws + 1280;
  float* ws_gi     = ws + 2304;
  float* ws_gh     = ws + 5376;
  float* ws_h      = ws + 8448;

  int t = threadIdx.x, lane = t&63;
  int gw = blockIdx.x*4 + (t>>6);
  int tok = min(max(tok_p[0], 0), VOCAB-1);
  __shared__ float sw[MAXLEN];

  // ---- Stage A: attn scores (waves 0..63) + gh = Whh@h (waves 1024..4095)
  if (gw < 64) {
    const float4* w4 = (const float4*)(attn_W + (size_t)gw*2048);
    const float4* e4 = (const float4*)(emb + (size_t)tok*HID);
    const float4* h4 = (const float4*)hidden;
    float acc = 0.f;
    #pragma unroll
    for (int j=0;j<4;j++) acc += dot4(w4[j*64+lane], e4[j*64+lane]);
    #pragma unroll
    for (int j=0;j<4;j++) acc += dot4(w4[(j+4)*64+lane], h4[j*64+lane]);
    acc = wave_sum(acc);
    if (lane==0) ws_scores[gw] = acc + attn_b[gw];
  } else if (gw >= 1024) {
    int row = gw - 1024;                       // 0..3071
    const float4* w4 = (const float4*)(Whh + (size_t)row*HID);
    const float4* h4 = (const float4*)hidden;
    float acc = 0.f;
    #pragma unroll
    for (int j=0;j<4;j++) acc += dot4(w4[j*64+lane], h4[j*64+lane]);
    acc = wave_sum(acc);
    if (lane==0) ws_gh[row] = acc + bhh[row];
  }
  gbar(bar+0, G_PRE);

  // ---- Stage B: softmax(64) + context = w @ enc, blocks 0..3 (256 cols each)
  if (blockIdx.x < 4) {
    if (t < 64) {
      float s = ws_scores[t];
      float m = s;
      #pragma unroll
      for (int k=32;k>=1;k>>=1) m = fmaxf(m, __shfl_xor(m,k));
      float e = expf(s-m);
      float d = e;
      #pragma unroll
      for (int k=32;k>=1;k>>=1) d += __shfl_xor(d,k);
      float w = e/d;
      sw[t] = w;
      if (blockIdx.x==0) out_attn[t] = w;
    }
    __syncthreads();
    int idx = blockIdx.x*256 + t;
    float acc = 0.f;
    #pragma unroll 8
    for (int p=0;p<MAXLEN;p++) acc += sw[p]*enc[p*HID + idx];
    ws_attn[idx] = acc;
  }
  gbar(bar+1, G_PRE);

  // ---- Stage C: x = relu(comb_W @ cat(emb,attn) + b), waves 0..1023
  if (gw < 1024) {
    const float4* w4 = (const float4*)(comb_W + (size_t)gw*2048);
    const float4* e4 = (const float4*)(emb + (size_t)tok*HID);
    const float4* a4 = (const float4*)ws_attn;
    float acc = 0.f;
    #pragma unroll
    for (int j=0;j<4;j++) acc += dot4(w4[j*64+lane],     e4[j*64+lane]);
    #pragma unroll
    for (int j=0;j<4;j++) acc += dot4(w4[(j+4)*64+lane], a4[j*64+lane]);
    acc = wave_sum(acc);
    if (lane==0) ws_x[gw] = fmaxf(acc + comb_b[gw], 0.f);
  }
  gbar(bar+2, G_PRE);

  // ---- Stage D: gi = Wih @ x, waves 0..3071
  if (gw < 3072) {
    const float4* w4 = (const float4*)(Wih + (size_t)gw*HID);
    const float4* x4 = (const float4*)ws_x;
    float acc = 0.f;
    #pragma unroll
    for (int j=0;j<4;j++) acc += dot4(w4[j*64+lane], x4[j*64+lane]);
    acc = wave_sum(acc);
    if (lane==0) ws_gi[gw] = acc + bih[gw];
  }
  gbar(bar+3, G_PRE);

  // ---- Stage E: GRU gates (r,z,n), blocks 0..3
  if (blockIdx.x < 4) {
    int i = blockIdx.x*256 + t;
    float r = 1.f/(1.f+expf(-(ws_gi[i]      + ws_gh[i])));
    float z = 1.f/(1.f+expf(-(ws_gi[HID+i]  + ws_gh[HID+i])));
    float n = tanhf(ws_gi[2*HID+i] + r*ws_gh[2*HID+i]);
    float h = hidden[i];
    float hn = (1.f-z)*n + z*h;
    ws_h[i]  = hn;
    out_h[i] = hn;
  }
}

// logits + per-block online stats + grid barrier + redundant LSE + subtract
__global__ __launch_bounds__(256,4) void k_logits_full(
    const float* out_W, const float* out_b,
    float* out_logp, unsigned* bar, float* ws)
{
  float* ws_h     = ws + 8448;
  float* ws_stats = ws + 9600;
  int t = threadIdx.x, lane = t&63, wv = t>>6;
  int gw = blockIdx.x*4 + wv;                 // 0..4095

  float hv[16];
  const float4* h4 = (const float4*)ws_h;
  #pragma unroll
  for (int c=0;c<4;c++){
    float4 v = h4[c*64+lane];
    hv[c*4+0]=v.x; hv[c*4+1]=v.y; hv[c*4+2]=v.z; hv[c*4+3]=v.w;
  }

  float lv[13];
  float m = -INFINITY, s = 0.f;
  int nr = 0;
  #pragma unroll 1
  for (int i=0;i<13;i++){
    int row = gw + 4096*i;
    if (row >= VOCAB) break;
    const float4* w4 = (const float4*)(out_W + (size_t)row*HID);
    float acc = 0.f;
    #pragma unroll
    for (int c=0;c<4;c++) acc += dot4f(w4[c*64+lane], hv + c*4);
    acc = wave_sum(acc);                       // all lanes hold dot
    float logit = acc + out_b[row];
    lv[i] = logit;
    if (logit > m) { s = s*expf(m-logit) + 1.f; m = logit; }
    else s += expf(logit-m);
    nr++;
  }

  __shared__ float sm[4], ss[4], flse;
  if (lane==0){ sm[wv]=m; ss[wv]=s; }
  __syncthreads();
  if (t==0){
    float M = fmaxf(fmaxf(sm[0],sm[1]),fmaxf(sm[2],sm[3]));
    float S = ss[0]*expf(sm[0]-M)+ss[1]*expf(sm[1]-M)
            + ss[2]*expf(sm[2]-M)+ss[3]*expf(sm[3]-M);
    ws_stats[blockIdx.x*2]   = M;
    ws_stats[blockIdx.x*2+1] = S;
  }
  gbar(bar+4, G_LOG);

  // every block redundantly reduces all 1024 {M,S} pairs -> lse (no 2nd barrier)
  float M = -INFINITY, S = 0.f;
  #pragma unroll
  for (int j=0;j<4;j++){
    int b = t*4 + j;
    float mi = ws_stats[b*2], si = ws_stats[b*2+1];
    float Mn = fmaxf(M, mi);
    S = S*expf(M-Mn) + si*expf(mi-Mn);
    M = Mn;
  }
  #pragma unroll
  for (int k=32;k>=1;k>>=1){
    float mo = __shfl_xor(M,k), so = __shfl_xor(S,k);
    float Mn = fmaxf(M,mo);
    S = S*expf(M-Mn) + so*expf(mo-Mn);
    M = Mn;
  }
  if (lane==0){ sm[wv]=M; ss[wv]=S; }
  __syncthreads();
  if (t==0){
    float Mf = fmaxf(fmaxf(sm[0],sm[1]),fmaxf(sm[2],sm[3]));
    float Sf = ss[0]*expf(sm[0]-Mf)+ss[1]*expf(sm[1]-Mf)
             + ss[2]*expf(sm[2]-Mf)+ss[3]*expf(sm[3]-Mf);
    flse = Mf + logf(Sf);
  }
  __syncthreads();
  float lse = flse;

  if (lane==0){
    #pragma unroll 1
    for (int i=0;i<nr;i++) out_logp[gw + 4096*i] = lv[i] - lse;
  }
}

extern "C" void kernel_launch(void* const* d_in, const int* in_sizes, int n_in,
                              void* d_out, int out_size, void* d_ws, size_t ws_size,
                              hipStream_t stream) {
  const int*   tok    = (const int*)d_in[0];
  const float* hidden = (const float*)d_in[1];
  const float* enc    = (const float*)d_in[2];
  const float* emb    = (const float*)d_in[3];
  const float* attn_W = (const float*)d_in[4];
  const float* attn_b = (const float*)d_in[5];
  const float* comb_W = (const float*)d_in[6];
  const float* comb_b = (const float*)d_in[7];
  const float* Wih    = (const float*)d_in[8];
  const float* Whh    = (const float*)d_in[9];
  const float* bih    = (const float*)d_in[10];
  const float* bhh    = (const float*)d_in[11];
  const float* out_W  = (const float*)d_in[12];
  const float* out_b  = (const float*)d_in[13];

  float* out      = (float*)d_out;
  float* out_logp = out;
  float* out_h    = out + VOCAB;
  float* out_attn = out + VOCAB + HID;

  float*    ws  = (float*)d_ws;
  unsigned* bar = (unsigned*)d_ws;

  k_init<<<1, 64, 0, stream>>>(bar);
  k_pre<<<G_PRE, 256, 0, stream>>>(tok, hidden, enc, emb, attn_W, attn_b,
                                   comb_W, comb_b, Wih, Whh, bih, bhh,
                                   out_h, out_attn, bar, ws);
  k_logits_full<<<G_LOG, 256, 0, stream>>>(out_W, out_b, out_logp, bar, ws);
}

// Round 4
// 429.872 us; speedup vs baseline: 2.2290x; 2.2290x over previous
//
#include <hip/hip_runtime.h>
#include <hip/hip_bf16.h>

#define VOCAB 50257
#define HID   1024
#define MAXLEN 64
#define FSTR  32            // uints between flags: 128B, one line per block
#define NB_PRE 256
#define NB_LOG 512
#define NT_LOG 512

__device__ __forceinline__ float dot4(float4 a, float4 b){
  return a.x*b.x + a.y*b.y + a.z*b.z + a.w*b.w;
}
__device__ __forceinline__ float wave_sum(float acc){
  #pragma unroll
  for (int k=32;k>=1;k>>=1) acc += __shfl_xor(acc,k);
  return acc;
}
__device__ __forceinline__ void st_ag(float* p, float v){
  __hip_atomic_store(p, v, __ATOMIC_RELAXED, __HIP_MEMORY_SCOPE_AGENT);
}
__device__ __forceinline__ float ld_ag(const float* p){
  return __hip_atomic_load((float*)p, __ATOMIC_RELAXED, __HIP_MEMORY_SCOPE_AGENT);
}

// Contention-free grid barrier: per-block flag on its own cacheline (plain
// store->flag via agent atomic after __syncthreads drains this block's vmem),
// wave0 polls all flags with relaxed agent atomic loads (coherence-point reads,
// no RMW serialization, no cache-maintenance storms).
__device__ __forceinline__ void barrier_flags(unsigned* flags, int nblk, unsigned val){
  __syncthreads();   // compiler emits s_waitcnt vmcnt(0) before s_barrier -> stores drained
  if (threadIdx.x == 0)
    __hip_atomic_store(flags + (size_t)blockIdx.x*FSTR, val,
                       __ATOMIC_RELAXED, __HIP_MEMORY_SCOPE_AGENT);
  if (threadIdx.x < 64){
    const int per = nblk >> 6;
    for(;;){
      bool ok = true;
      for (int j=0;j<per;j++){
        unsigned f = __hip_atomic_load(flags + (size_t)(threadIdx.x*per + j)*FSTR,
                                       __ATOMIC_RELAXED, __HIP_MEMORY_SCOPE_AGENT);
        ok &= (f == val);
      }
      if (__all(ok)) break;
      __builtin_amdgcn_s_sleep(1);
    }
  }
  __syncthreads();
}

// ws layout (uint/float index):
//   [0      .. 32768)  : k_pre flags, 4 sites x 256 blocks x FSTR
//   [32768  .. 49152)  : k_logits flags, 512 blocks x FSTR
//   float D = ws + 81920:
//     scores D+0(64), attn D+64(1024), x D+1088(1024), gi D+2112(3072),
//     gh D+5184(3072), h D+8256(1024), stats D+9280(1024)
#define WS_D 81920

__global__ __launch_bounds__(256) void k_pre(
    const int* tok_p, const float* hidden, const float* enc, const float* emb,
    const float* attn_W, const float* attn_b,
    const float* comb_W, const float* comb_b,
    const float* Wih, const float* Whh, const float* bih, const float* bhh,
    float* out_h, float* out_attn, float* ws)
{
  unsigned* fl = (unsigned*)ws;
  float* D        = ws + WS_D;
  float* s_scores = D;
  float* s_attn   = D + 64;
  float* s_x      = D + 1088;
  float* s_gi     = D + 2112;
  float* s_gh     = D + 5184;
  float* s_h      = D + 8256;

  __shared__ float lds[HID];
  __shared__ float sw[MAXLEN];

  int t = threadIdx.x, lane = t&63;
  int gw = blockIdx.x*4 + (t>>6);            // 0..1023
  int tok = min(max(tok_p[0], 0), VOCAB-1);
  const float4* e4 = (const float4*)(emb + (size_t)tok*HID);
  const float4* h4 = (const float4*)hidden;

  // ---- Stage A: attn scores (waves 0..63) + gh = Whh@h + bhh (3 rows/wave)
  if (gw < 64){
    const float4* w4 = (const float4*)(attn_W + (size_t)gw*2048);
    float acc = 0.f;
    #pragma unroll
    for (int j=0;j<4;j++) acc += dot4(w4[j*64+lane],     e4[j*64+lane]);
    #pragma unroll
    for (int j=0;j<4;j++) acc += dot4(w4[(j+4)*64+lane], h4[j*64+lane]);
    acc = wave_sum(acc);
    if (lane==0) st_ag(&s_scores[gw], acc + attn_b[gw]);
  }
  #pragma unroll 1
  for (int r = gw; r < 3*HID; r += 1024){
    const float4* w4 = (const float4*)(Whh + (size_t)r*HID);
    float acc = 0.f;
    #pragma unroll
    for (int j=0;j<4;j++) acc += dot4(w4[j*64+lane], h4[j*64+lane]);
    acc = wave_sum(acc);
    if (lane==0) st_ag(&s_gh[r], acc + bhh[r]);
  }
  barrier_flags(fl + 0*NB_PRE*FSTR, NB_PRE, 1u);

  // ---- Stage B: softmax(64) + context = w @ enc (blocks 0..3, 256 cols each)
  if (blockIdx.x < 4){
    if (t < 64){
      float s = ld_ag(&s_scores[t]);
      float m = s;
      #pragma unroll
      for (int k=32;k>=1;k>>=1) m = fmaxf(m, __shfl_xor(m,k));
      float e = expf(s-m), d = e;
      #pragma unroll
      for (int k=32;k>=1;k>>=1) d += __shfl_xor(d,k);
      float w = e/d;
      sw[t] = w;
      if (blockIdx.x==0) out_attn[t] = w;
    }
    __syncthreads();
    int col = blockIdx.x*256 + t;
    float acc = 0.f;
    #pragma unroll 8
    for (int p=0;p<MAXLEN;p++) acc += sw[p]*enc[p*HID + col];
    st_ag(&s_attn[col], acc);
  }
  barrier_flags(fl + 1*NB_PRE*FSTR, NB_PRE, 2u);

  // ---- Stage C: x = relu(comb_W @ cat(emb,attn) + b), 1 row/wave
  #pragma unroll
  for (int j=0;j<4;j++) lds[j*256+t] = ld_ag(&s_attn[j*256+t]);
  __syncthreads();
  {
    const float4* w4 = (const float4*)(comb_W + (size_t)gw*2048);
    const float4* l4 = (const float4*)lds;
    float acc = 0.f;
    #pragma unroll
    for (int j=0;j<4;j++) acc += dot4(w4[j*64+lane],     e4[j*64+lane]);
    #pragma unroll
    for (int j=0;j<4;j++) acc += dot4(w4[(j+4)*64+lane], l4[j*64+lane]);
    acc = wave_sum(acc);
    if (lane==0) st_ag(&s_x[gw], fmaxf(acc + comb_b[gw], 0.f));
  }
  barrier_flags(fl + 2*NB_PRE*FSTR, NB_PRE, 3u);

  // ---- Stage D: gi = Wih @ x + bih, 3 rows/wave
  #pragma unroll
  for (int j=0;j<4;j++) lds[j*256+t] = ld_ag(&s_x[j*256+t]);
  __syncthreads();
  {
    const float4* l4 = (const float4*)lds;
    #pragma unroll 1
    for (int r = gw; r < 3*HID; r += 1024){
      const float4* w4 = (const float4*)(Wih + (size_t)r*HID);
      float acc = 0.f;
      #pragma unroll
      for (int j=0;j<4;j++) acc += dot4(w4[j*64+lane], l4[j*64+lane]);
      acc = wave_sum(acc);
      if (lane==0) st_ag(&s_gi[r], acc + bih[r]);
    }
  }
  barrier_flags(fl + 3*NB_PRE*FSTR, NB_PRE, 4u);

  // ---- Stage E: GRU gates (r,z,n) -> h_new (blocks 0..3)
  if (blockIdx.x < 4){
    int i = blockIdx.x*256 + t;
    float gi0 = ld_ag(&s_gi[i]),       gh0 = ld_ag(&s_gh[i]);
    float gi1 = ld_ag(&s_gi[HID+i]),   gh1 = ld_ag(&s_gh[HID+i]);
    float gi2 = ld_ag(&s_gi[2*HID+i]), gh2 = ld_ag(&s_gh[2*HID+i]);
    float r = 1.f/(1.f+expf(-(gi0+gh0)));
    float z = 1.f/(1.f+expf(-(gi1+gh1)));
    float n = tanhf(gi2 + r*gh2);
    float h = hidden[i];
    float hn = (1.f-z)*n + z*h;
    s_h[i]  = hn;      // plain: consumed by next kernel (stream order flush)
    out_h[i] = hn;
  }
}

// logits + block stats + flag barrier + redundant LSE + subtract (regs held)
__global__ __launch_bounds__(NT_LOG,4) void k_logits_full(
    const float* out_W, const float* out_b, float* out_logp, float* ws)
{
  unsigned* fl = (unsigned*)ws + 4*NB_PRE*FSTR;
  float* D       = ws + WS_D;
  float* s_h     = D + 8256;
  float* s_stats = D + 9280;

  __shared__ float lh[HID];
  __shared__ float sm[8], ss[8], flse;

  int t = threadIdx.x, lane = t&63, wv = t>>6;
  lh[t] = s_h[t]; lh[512+t] = s_h[512+t];
  __syncthreads();

  float hv[16];
  {
    const float4* l4 = (const float4*)lh;
    #pragma unroll
    for (int c=0;c<4;c++){
      float4 v = l4[c*64+lane];
      hv[c*4+0]=v.x; hv[c*4+1]=v.y; hv[c*4+2]=v.z; hv[c*4+3]=v.w;
    }
  }

  int gw = blockIdx.x*8 + wv;                // 0..4095
  float lv[13];
  float m = -INFINITY, s = 0.f;
  int nr = 0;

  float4 q[4];
  {
    const float4* w4 = (const float4*)(out_W + (size_t)gw*HID);
    #pragma unroll
    for (int c=0;c<4;c++) q[c] = w4[c*64+lane];
  }
  #pragma unroll 1
  for (int i=0;i<13;i++){
    int row = gw + 4096*i;
    if (row >= VOCAB) break;
    int nrow = row + 4096;
    float4 qn[4];
    if (nrow < VOCAB){
      const float4* w4 = (const float4*)(out_W + (size_t)nrow*HID);
      #pragma unroll
      for (int c=0;c<4;c++) qn[c] = w4[c*64+lane];   // prefetch overlaps shuffles
    }
    float acc = 0.f;
    #pragma unroll
    for (int c=0;c<4;c++)
      acc += q[c].x*hv[c*4+0] + q[c].y*hv[c*4+1] + q[c].z*hv[c*4+2] + q[c].w*hv[c*4+3];
    acc = wave_sum(acc);
    float logit = acc + out_b[row];            // broadcast scalar load
    lv[i] = logit; nr++;
    if (logit > m) { s = s*expf(m-logit) + 1.f; m = logit; }
    else s += expf(logit-m);
    #pragma unroll
    for (int c=0;c<4;c++) q[c] = qn[c];
  }

  if (lane==0){ sm[wv]=m; ss[wv]=s; }
  __syncthreads();
  if (t==0){
    float M = -INFINITY, S = 0.f;
    #pragma unroll
    for (int w=0;w<8;w++){
      float Mn = fmaxf(M, sm[w]);
      S = S*expf(M-Mn) + ss[w]*expf(sm[w]-Mn);
      M = Mn;
    }
    st_ag(&s_stats[blockIdx.x*2],   M);
    st_ag(&s_stats[blockIdx.x*2+1], S);
  }
  barrier_flags(fl, NB_LOG, 1u);

  // every block redundantly reduces 512 {M,S} pairs (1 per thread)
  float M = ld_ag(&s_stats[2*t]);
  float S = ld_ag(&s_stats[2*t+1]);
  #pragma unroll
  for (int k=32;k>=1;k>>=1){
    float mo = __shfl_xor(M,k), so = __shfl_xor(S,k);
    float Mn = fmaxf(M,mo);
    S = S*expf(M-Mn) + so*expf(mo-Mn);
    M = Mn;
  }
  if (lane==0){ sm[wv]=M; ss[wv]=S; }
  __syncthreads();
  if (t==0){
    float Mf = -INFINITY, Sf = 0.f;
    #pragma unroll
    for (int w=0;w<8;w++){
      float Mn = fmaxf(Mf, sm[w]);
      Sf = Sf*expf(Mf-Mn) + ss[w]*expf(sm[w]-Mn);
      Mf = Mn;
    }
    flse = Mf + logf(Sf);
  }
  __syncthreads();
  float lse = flse;

  if (lane==0){
    #pragma unroll 1
    for (int i=0;i<nr;i++) out_logp[gw + 4096*i] = lv[i] - lse;
  }
}

extern "C" void kernel_launch(void* const* d_in, const int* in_sizes, int n_in,
                              void* d_out, int out_size, void* d_ws, size_t ws_size,
                              hipStream_t stream) {
  const int*   tok    = (const int*)d_in[0];
  const float* hidden = (const float*)d_in[1];
  const float* enc    = (const float*)d_in[2];
  const float* emb    = (const float*)d_in[3];
  const float* attn_W = (const float*)d_in[4];
  const float* attn_b = (const float*)d_in[5];
  const float* comb_W = (const float*)d_in[6];
  const float* comb_b = (const float*)d_in[7];
  const float* Wih    = (const float*)d_in[8];
  const float* Whh    = (const float*)d_in[9];
  const float* bih    = (const float*)d_in[10];
  const float* bhh    = (const float*)d_in[11];
  const float* out_W  = (const float*)d_in[12];
  const float* out_b  = (const float*)d_in[13];

  float* out      = (float*)d_out;
  float* out_logp = out;
  float* out_h    = out + VOCAB;
  float* out_attn = out + VOCAB + HID;

  float* ws = (float*)d_ws;

  k_pre<<<NB_PRE, 256, 0, stream>>>(tok, hidden, enc, emb, attn_W, attn_b,
                                    comb_W, comb_b, Wih, Whh, bih, bhh,
                                    out_h, out_attn, ws);
  k_logits_full<<<NB_LOG, NT_LOG, 0, stream>>>(out_W, out_b, out_logp, ws);
}